// Round 4
// baseline (149.279 us; speedup 1.0000x reference)
//
#include <hip/hip_runtime.h>
#include <hip/hip_bf16.h>
#include <stdint.h>
#include <stddef.h>

// MHA fwd: B=2 S=2048 D=1024 H=16 DK=64.
// wt (W->Wt bf16) + cvt (q/k/v fp32->bf16) -> gemm_qkv (pure-bf16 m97-style)
// -> flash (4 waves = 2 qhalf x 2 kvhalf over 64 q-rows, KVBLK=64, shared
//    staged K/Vt, swapped 32x32x16 QK^T, exp2 softmax, LDS end-combine)
// -> gemm_o (64x128 tile).
//
// R4: flash was the wall (61us, Occupancy 18%, VALU 48%): grid 512 = 2
// blocks/CU = 8 waves/CU, latency-bound. Split each block's work 2x2
// (qhalf x kvhalf): grid 1024 = 4 blocks/CU = 16 waves/CU, per-wave chain
// halved (4 QKT mfma + 16 exp + 4 PV mfma per iter). kv-half partials
// (unnormalized O + denom) combined via LDS at the end - no extra HBM.
// gemm_o: was 256 blocks = 1/CU; retiled 128x128 -> 64x128 (512 blocks).

typedef __bf16 bf16;
typedef __attribute__((ext_vector_type(4))) bf16 bf16x4;
typedef __attribute__((ext_vector_type(8))) bf16 bf16x8;
typedef __attribute__((ext_vector_type(4))) float f32x4;
typedef __attribute__((ext_vector_type(16))) float f32x16;
typedef __attribute__((ext_vector_type(2))) unsigned int uint2v;

#define DEVINL static __device__ __forceinline__

DEVINL void gload_lds16(const void* g, void* l) {
  __builtin_amdgcn_global_load_lds(
      (const __attribute__((address_space(1))) void*)g,
      (__attribute__((address_space(3))) void*)l, 16, 0, 0);
}

DEVINL f32x4 mfma16(bf16x8 a, bf16x8 b, f32x4 c) {
  return __builtin_amdgcn_mfma_f32_16x16x32_bf16(a, b, c, 0, 0, 0);
}
DEVINL f32x16 mfma32(bf16x8 a, bf16x8 b, f32x16 c) {
  return __builtin_amdgcn_mfma_f32_32x32x16_bf16(a, b, c, 0, 0, 0);
}
// v_exp_f32 computes 2^x; log2(e) is folded into the Q pre-scale.
DEVINL float fexp2(float x) {
  float r;
  asm("v_exp_f32 %0, %1" : "=v"(r) : "v"(x));
  return r;
}
// RNE f32->bf16 pair pack via compiler casts (m240: don't hand-write cvt_pk).
DEVINL unsigned pack2(float lo, float hi) {
  union { bf16 h[2]; unsigned u; } t;
  t.h[0] = (bf16)lo; t.h[1] = (bf16)hi;
  return t.u;
}
DEVINL bf16x8 mk8(unsigned a, unsigned b, unsigned c, unsigned d) {
  union { unsigned u[4]; bf16x8 v; } t;
  t.u[0] = a; t.u[1] = b; t.u[2] = c; t.u[3] = d;
  return t.v;
}

// ---------------------------------------------------------------------------
// Kernel 1: weight transpose+convert. W[k][n] fp32 -> Wt[t][n][k] bf16
// ---------------------------------------------------------------------------
__global__ __launch_bounds__(256) void wt_kernel(
    const float* __restrict__ w0, const float* __restrict__ w1,
    const float* __restrict__ w2, const float* __restrict__ w3,
    bf16* __restrict__ out) {
  __shared__ float tile[64 * 65];
  int t = blockIdx.y;
  const float* w = (t == 0) ? w0 : (t == 1) ? w1 : (t == 2) ? w2 : w3;
  bf16* o = out + (size_t)t * 1024 * 1024;
  int tb = blockIdx.x;
  int k0 = (tb >> 4) * 64, n0 = (tb & 15) * 64;
  int c = threadIdx.x & 63, r0 = threadIdx.x >> 6;
  for (int r = r0; r < 64; r += 4)
    tile[r * 65 + c] = w[(size_t)(k0 + r) * 1024 + n0 + c];
  __syncthreads();
  for (int r = r0; r < 64; r += 4)
    o[(size_t)(n0 + r) * 1024 + k0 + c] = (bf16)tile[c * 65 + r];
}

// ---------------------------------------------------------------------------
// Kernel 1b: q/k/v fp32 -> bf16 (streaming, vectorized).
// ---------------------------------------------------------------------------
__global__ __launch_bounds__(256) void cvt_kernel(
    const float* __restrict__ q, const float* __restrict__ k,
    const float* __restrict__ v, bf16* __restrict__ out) {
  int z = blockIdx.y;
  const float* src = (z == 0) ? q : (z == 1) ? k : v;
  size_t off = ((size_t)blockIdx.x * 256 + threadIdx.x) * 8;
  f32x4 a = *(const f32x4*)(src + off);
  f32x4 b = *(const f32x4*)(src + off + 4);
  bf16x8 h;
#pragma unroll
  for (int j = 0; j < 4; ++j) { h[j] = (bf16)a[j]; h[4 + j] = (bf16)b[j]; }
  *(bf16x8*)(out + (size_t)z * 4194304 + off) = h;
}

// ---------------------------------------------------------------------------
// Kernel 2: QKV projection GEMM (pure bf16, m97 structure).
// Q scaled by 0.125*log2e in epilogue -> Qp; K -> Kp; V transposed -> Vt.
// ---------------------------------------------------------------------------
__global__ __launch_bounds__(256) void gemm_qkv(
    const bf16* __restrict__ Abf, const bf16* __restrict__ Wt,
    const float* __restrict__ bq, const float* __restrict__ bk,
    const float* __restrict__ bv,
    bf16* __restrict__ outQ, bf16* __restrict__ outK, bf16* __restrict__ Vt) {
  int z = blockIdx.z;
  const bf16* A    = Abf + (size_t)z * 4194304;
  const bf16* Wz   = Wt + (size_t)z * 1024 * 1024;
  const float* bia = (z == 0) ? bq : (z == 1) ? bk : bv;
  float scale      = (z == 0) ? 0.18033688011112042f : 1.0f;  // 0.125*log2(e)

  __shared__ bf16 As[2][128 * 32];
  __shared__ bf16 Bs[2][128 * 32];

  int m0 = blockIdx.x * 128, n0 = blockIdx.y * 128;
  int tid = threadIdx.x, w = tid >> 6, l = tid & 63;
  int wm = (w >> 1) * 64, wn = (w & 1) * 64;
  int c16 = l & 15, g = l >> 4;
  int rsw = (c16 >> 1) & 3;

  int brow0 = (w * 2 + 0) * 16 + (l >> 2);
  int brow1 = (w * 2 + 1) * 16 + (l >> 2);
  int bk0 = ((l & 3) ^ ((brow0 >> 1) & 3)) * 8;
  int bk1 = ((l & 3) ^ ((brow1 >> 1) & 3)) * 8;

  f32x4 acc[4][4] = {};

#define STAGE_QKV(buf, kt)                                                   \
  do {                                                                       \
    gload_lds16(A + (size_t)(m0 + brow0) * 1024 + (kt) + bk0,                \
                (char*)As[buf] + (w * 2 + 0) * 1024 + l * 16);               \
    gload_lds16(A + (size_t)(m0 + brow1) * 1024 + (kt) + bk1,                \
                (char*)As[buf] + (w * 2 + 1) * 1024 + l * 16);               \
    gload_lds16(Wz + (size_t)(n0 + brow0) * 1024 + (kt) + bk0,               \
                (char*)Bs[buf] + (w * 2 + 0) * 1024 + l * 16);               \
    gload_lds16(Wz + (size_t)(n0 + brow1) * 1024 + (kt) + bk1,               \
                (char*)Bs[buf] + (w * 2 + 1) * 1024 + l * 16);               \
  } while (0)

  STAGE_QKV(0, 0);
  __syncthreads();

  int cur = 0;
  for (int kt = 0; kt < 1024; kt += 32) {
    if (kt < 992) STAGE_QKV(cur ^ 1, kt + 32);
    bf16x8 af[4], bfr[4];
#pragma unroll
    for (int mt = 0; mt < 4; ++mt)
      af[mt] = *(const bf16x8*)&As[cur][(wm + mt * 16 + c16) * 32 + ((g ^ rsw) * 8)];
#pragma unroll
    for (int nt = 0; nt < 4; ++nt)
      bfr[nt] = *(const bf16x8*)&Bs[cur][(wn + nt * 16 + c16) * 32 + ((g ^ rsw) * 8)];
#pragma unroll
    for (int mt = 0; mt < 4; ++mt)
#pragma unroll
      for (int nt = 0; nt < 4; ++nt)
        acc[mt][nt] = mfma16(af[mt], bfr[nt], acc[mt][nt]);
    __syncthreads();  // drains vmcnt -> next buffer staged
    cur ^= 1;
  }
#undef STAGE_QKV

  if (z < 2) {
    bf16* Cout = (z == 0) ? outQ : outK;
#pragma unroll
    for (int mt = 0; mt < 4; ++mt)
#pragma unroll
      for (int nt = 0; nt < 4; ++nt) {
        int n = n0 + wn + nt * 16 + c16;
        float bb = bia[n];
#pragma unroll
        for (int r = 0; r < 4; ++r) {
          int m = m0 + wm + mt * 16 + g * 4 + r;
          Cout[(size_t)m * 1024 + n] = (bf16)((acc[mt][nt][r] + bb) * scale);
        }
      }
  } else {
    // V: write transposed -> Vt[(b*16+h)*64 + dk][s], 4 consecutive s per lane
#pragma unroll
    for (int mt = 0; mt < 4; ++mt)
#pragma unroll
      for (int nt = 0; nt < 4; ++nt) {
        int n = n0 + wn + nt * 16 + c16;       // h*64 + dk
        float bb = bia[n];
        int m = m0 + wm + mt * 16 + g * 4;     // b*2048 + s (4-aligned)
        int b = m >> 11, s = m & 2047;
        bf16x4 v;
#pragma unroll
        for (int r = 0; r < 4; ++r) v[r] = (bf16)(acc[mt][nt][r] + bb);
        *(bf16x4*)&Vt[((size_t)(b * 16 + (n >> 6)) * 64 + (n & 63)) * 2048 + s] = v;
      }
  }
}

// ---------------------------------------------------------------------------
// Kernel 3: flash attention. Block = (b,h,64 q-rows); 4 waves = 2 qhalf x
// 2 kvhalf. KVBLK=64 staged in LDS (K [s][dk], Vt [dk][s]) double-buffered,
// XOR-swizzled, shared by all 4 waves. Each wave: one 32x32 S^T tile
// (mfma32(K,Q) swapped), exp2, pack+permlane32_swap, PV into unnormalized O.
// kv-half partials (O, denom) combined via LDS at the end.
// ---------------------------------------------------------------------------
__global__ __launch_bounds__(256) void flash_kernel(
    const bf16* __restrict__ Qp, const bf16* __restrict__ Kp,
    const bf16* __restrict__ Vt, bf16* __restrict__ AO) {
  __shared__ __align__(16) bf16 Ks[2][64 * 64];
  __shared__ __align__(16) bf16 Vs[2][64 * 64];

  int orig = blockIdx.x;
  int wg = (orig & 7) * 128 + (orig >> 3);   // XCD-chunked, bijective (1024%8==0)
  int bh = wg >> 5, qb = wg & 31;
  int b = bh >> 4, h = bh & 15;
  int tid = threadIdx.x, w = tid >> 6, l = tid & 63;
  int lo5 = l & 31, g = l >> 5;
  int qhalf = w >> 1, kvhalf = w & 1;
  int q0 = qb * 64 + qhalf * 32;

  // Q as B-fragments: qf[kt] = Q[q0+lo5][kt*16 + g*8 + j]
  const bf16* qptr = Qp + (size_t)(b * 2048 + q0 + lo5) * 1024 + h * 64 + g * 8;
  bf16x8 qf0 = *(const bf16x8*)(qptr + 0);
  bf16x8 qf1 = *(const bf16x8*)(qptr + 16);
  bf16x8 qf2 = *(const bf16x8*)(qptr + 32);
  bf16x8 qf3 = *(const bf16x8*)(qptr + 48);

  const bf16* kbase = Kp + (size_t)(b * 2048) * 1024 + h * 64;
  const bf16* vbase = Vt + (size_t)bh * 64 * 2048;

  // staging indices: unit u in [0,512): row=u>>3, col unit c=u&7, source col c^(row&7)
  int u0 = w * 64 + l;
  int u1 = (4 + w) * 64 + l;
  int r0s = u0 >> 3, c0s = (u0 & 7) ^ (r0s & 7);
  int r1s = u1 >> 3, c1s = (u1 & 7) ^ (r1s & 7);

#define STAGE(buf, s0)                                                          \
  do {                                                                          \
    gload_lds16(kbase + (size_t)((s0) + r0s) * 1024 + c0s * 8,                  \
                (bf16*)Ks[buf] + u0 * 8);                                       \
    gload_lds16(kbase + (size_t)((s0) + r1s) * 1024 + c1s * 8,                  \
                (bf16*)Ks[buf] + u1 * 8);                                       \
    gload_lds16(vbase + (size_t)r0s * 2048 + (s0) + c0s * 8,                    \
                (bf16*)Vs[buf] + u0 * 8);                                       \
    gload_lds16(vbase + (size_t)r1s * 2048 + (s0) + c1s * 8,                    \
                (bf16*)Vs[buf] + u1 * 8);                                       \
  } while (0)

#define LDSK(cp, nt, kt) \
  (*(const bf16x8*)&cp[(((nt)*32 + lo5) << 6) + (((((kt)*2 + g)) ^ (lo5 & 7)) << 3)])
#define LDSV(cp, dt, st) \
  (*(const bf16x8*)&cp[(((dt)*32 + lo5) << 6) + (((((st)*2 + g)) ^ (lo5 & 7)) << 3)])

  f32x16 o0 = {}, o1 = {};
  float ps0 = 0.f, ps1 = 0.f, ps2 = 0.f, ps3 = 0.f;

  STAGE(0, 0);
  int cur = 0;
  for (int t = 0; t < 32; ++t) {
    if (t < 31) {
      STAGE(cur ^ 1, (t + 1) * 64);
      asm volatile("s_waitcnt vmcnt(4)" ::: "memory");
    } else {
      asm volatile("s_waitcnt vmcnt(0)" ::: "memory");
    }
    __builtin_amdgcn_s_barrier();
    __builtin_amdgcn_sched_barrier(0);
    const bf16* kc = Ks[cur];
    const bf16* vc = Vs[cur];

    // ---- S^T tile (k_local = kvhalf*32 + 0..31; row=k, col=q=lo5) ----
    f32x16 sv = {};
    __builtin_amdgcn_s_setprio(1);
    sv = mfma32(LDSK(kc, kvhalf, 0), qf0, sv);
    sv = mfma32(LDSK(kc, kvhalf, 1), qf1, sv);
    sv = mfma32(LDSK(kc, kvhalf, 2), qf2, sv);
    sv = mfma32(LDSK(kc, kvhalf, 3), qf3, sv);
    __builtin_amdgcn_s_setprio(0);
    float p[16];
#pragma unroll
    for (int r = 0; r < 16; ++r) p[r] = fexp2(sv[r]);
    ps0 += p[0] + p[4] + p[8] + p[12];
    ps1 += p[1] + p[5] + p[9] + p[13];
    ps2 += p[2] + p[6] + p[10] + p[14];
    ps3 += p[3] + p[7] + p[11] + p[15];
    unsigned pw0 = pack2(p[0], p[1]), pw1 = pack2(p[2], p[3]);
    unsigned pw2 = pack2(p[4], p[5]), pw3 = pack2(p[6], p[7]);
    unsigned pw4 = pack2(p[8], p[9]), pw5 = pack2(p[10], p[11]);
    unsigned pw6 = pack2(p[12], p[13]), pw7 = pack2(p[14], p[15]);
    uint2v a02 = __builtin_amdgcn_permlane32_swap(pw0, pw2, false, false);
    uint2v a13 = __builtin_amdgcn_permlane32_swap(pw1, pw3, false, false);
    uint2v a46 = __builtin_amdgcn_permlane32_swap(pw4, pw6, false, false);
    uint2v a57 = __builtin_amdgcn_permlane32_swap(pw5, pw7, false, false);
    bf16x8 pa0 = mk8(a02.x, a13.x, a02.y, a13.y);  // s kvhalf*32 + 0..15
    bf16x8 pa1 = mk8(a46.x, a57.x, a46.y, a57.y);  // s kvhalf*32 + 16..31

    // ---- O += P V (V s-range kvhalf*32..+31) ----
    __builtin_amdgcn_s_setprio(1);
    o0 = mfma32(pa0, LDSV(vc, 0, kvhalf * 2 + 0), o0);
    o1 = mfma32(pa0, LDSV(vc, 1, kvhalf * 2 + 0), o1);
    o0 = mfma32(pa1, LDSV(vc, 0, kvhalf * 2 + 1), o0);
    o1 = mfma32(pa1, LDSV(vc, 1, kvhalf * 2 + 1), o1);
    __builtin_amdgcn_s_setprio(0);

    __builtin_amdgcn_sched_barrier(0);
    __builtin_amdgcn_s_barrier();
    cur ^= 1;
  }
#undef STAGE
#undef LDSK
#undef LDSV

  // per-kv-half denominator: tot on lane l covers q = q0 + (l&31)
  float plsum = (ps0 + ps1) + (ps2 + ps3);
  float tot = plsum + __shfl_xor(plsum, 32);

  // ---- combine kv halves via LDS (reuse Ks as f32[2][64][32], Vs for denoms)
  float* ored = (float*)Ks;   // exactly 16 KB = 2*64*32 floats
  float* dred = (float*)Vs;
  if (kvhalf) {
    float* dst = ored + (qhalf * 64 + l) * 32;
#pragma unroll
    for (int c = 0; c < 8; ++c) {      // rotation-swizzled 16B chunks
      int base = ((c + l) & 7) * 4;
#pragma unroll
      for (int j = 0; j < 4; ++j)
        dst[base + j] = (c < 4) ? o0[c * 4 + j] : o1[(c - 4) * 4 + j];
    }
    dred[qhalf * 64 + l] = tot;
  }
  __syncthreads();
  if (!kvhalf) {
    const float* src = ored + (qhalf * 64 + l) * 32;
#pragma unroll
    for (int c = 0; c < 8; ++c) {
      int base = ((c + l) & 7) * 4;
#pragma unroll
      for (int j = 0; j < 4; ++j) {
        float v = src[base + j];
        if (c < 4) o0[c * 4 + j] += v; else o1[(c - 4) * 4 + j] += v;
      }
    }
    float tot2 = tot + dred[qhalf * 64 + l];
#pragma unroll
    for (int r = 0; r < 16; ++r) {
      int qr = (r & 3) + 8 * (r >> 2) + 4 * g;        // output row of o0[r]/o1[r]
      float inv = 1.0f / __shfl(tot2, qr);            // row qr's denominator
      bf16* op = AO + (size_t)(b * 2048 + q0 + qr) * 1024 + h * 64 + lo5;
      op[0]  = (bf16)(o0[r] * inv);
      op[32] = (bf16)(o1[r] * inv);
    }
  }
}

// ---------------------------------------------------------------------------
// Kernel 4: output projection, 64x128 tile (512 blocks = 2/CU), m97 structure,
// swizzled LDS. fp32 out + bias.
// ---------------------------------------------------------------------------
__global__ __launch_bounds__(256) void gemm_o(
    const bf16* __restrict__ A, const bf16* __restrict__ Wt3,
    const float* __restrict__ bo, float* __restrict__ C) {
  __shared__ bf16 As[2][64 * 32];
  __shared__ bf16 Bs[2][128 * 32];
  int m0 = blockIdx.x * 64, n0 = blockIdx.y * 128;
  int tid = threadIdx.x, w = tid >> 6, l = tid & 63;
  int wm = (w >> 1) * 32, wn = (w & 1) * 64;
  int c16 = l & 15, g = l >> 4;
  int rsw = (c16 >> 1) & 3;

  // A staging: 1 chunk/lane. row = tid>>2, phys chunk = tid&3
  int arow = tid >> 2, akc = tid & 3;
  int asrc = (akc ^ ((arow >> 1) & 3)) * 8;
  // B staging: 2 chunks/lane
  int brow0 = (w * 2 + 0) * 16 + (l >> 2);
  int brow1 = (w * 2 + 1) * 16 + (l >> 2);
  int bk0 = ((l & 3) ^ ((brow0 >> 1) & 3)) * 8;
  int bk1 = ((l & 3) ^ ((brow1 >> 1) & 3)) * 8;

  f32x4 acc[2][4] = {};

#define STAGE_O(buf, kt)                                                     \
  do {                                                                       \
    gload_lds16(A + (size_t)(m0 + arow) * 1024 + (kt) + asrc,                \
                (char*)As[buf] + tid * 16);                                  \
    gload_lds16(Wt3 + (size_t)(n0 + brow0) * 1024 + (kt) + bk0,              \
                (char*)Bs[buf] + (w * 2 + 0) * 1024 + l * 16);               \
    gload_lds16(Wt3 + (size_t)(n0 + brow1) * 1024 + (kt) + bk1,              \
                (char*)Bs[buf] + (w * 2 + 1) * 1024 + l * 16);               \
  } while (0)

  STAGE_O(0, 0);
  __syncthreads();

  int cur = 0;
  for (int kt = 0; kt < 1024; kt += 32) {
    if (kt < 992) STAGE_O(cur ^ 1, kt + 32);
    bf16x8 af[2], bfr[4];
#pragma unroll
    for (int mt = 0; mt < 2; ++mt)
      af[mt] = *(const bf16x8*)&As[cur][(wm + mt * 16 + c16) * 32 + ((g ^ rsw) * 8)];
#pragma unroll
    for (int nt = 0; nt < 4; ++nt)
      bfr[nt] = *(const bf16x8*)&Bs[cur][(wn + nt * 16 + c16) * 32 + ((g ^ rsw) * 8)];
#pragma unroll
    for (int mt = 0; mt < 2; ++mt)
#pragma unroll
      for (int nt = 0; nt < 4; ++nt)
        acc[mt][nt] = mfma16(af[mt], bfr[nt], acc[mt][nt]);
    __syncthreads();  // drains vmcnt -> next buffer staged
    cur ^= 1;
  }
#undef STAGE_O

#pragma unroll
  for (int mt = 0; mt < 2; ++mt)
#pragma unroll
    for (int nt = 0; nt < 4; ++nt) {
      int n = n0 + wn + nt * 16 + c16;
      float bb = bo[n];
#pragma unroll
      for (int r = 0; r < 4; ++r) {
        int m = m0 + wm + mt * 16 + g * 4 + r;
        C[(size_t)m * 1024 + n] = acc[mt][nt][r] + bb;
      }
    }
}

// ---------------------------------------------------------------------------
extern "C" void kernel_launch(void* const* d_in, const int* in_sizes, int n_in,
                              void* d_out, int out_size, void* d_ws, size_t ws_size,
                              hipStream_t stream) {
  const float* query = (const float*)d_in[0];
  const float* key_  = (const float*)d_in[1];
  const float* value = (const float*)d_in[2];
  const float* Wq = (const float*)d_in[3];
  const float* bq = (const float*)d_in[4];
  const float* Wk = (const float*)d_in[5];
  const float* bk = (const float*)d_in[6];
  const float* Wv = (const float*)d_in[7];
  const float* bv = (const float*)d_in[8];
  const float* Wo = (const float*)d_in[9];
  const float* bo = (const float*)d_in[10];
  float* out = (float*)d_out;

  char* ws = (char*)d_ws;
  const size_t MB = 1024 * 1024;
  bf16* Wt  = (bf16*)(ws);              // 4 x [1024][1024] bf16 = 8 MB
  bf16* Abf = (bf16*)(ws + 8 * MB);     // 3 x [4096][1024] bf16 = 24 MB
  bf16* Qp  = (bf16*)(ws + 32 * MB);    // [4096][1024] bf16 (pre-scaled)
  bf16* Kp  = (bf16*)(ws + 40 * MB);    // [4096][1024]
  bf16* Vt  = (bf16*)(ws + 48 * MB);    // [32][64][2048]
  bf16* AO  = (bf16*)(ws + 8 * MB);     // attn out [4096][1024] (reuses Abf)

  dim3 blk(256);
  wt_kernel<<<dim3(256, 4), blk, 0, stream>>>(Wq, Wk, Wv, Wo, Wt);
  cvt_kernel<<<dim3(2048, 3), blk, 0, stream>>>(query, key_, value, Abf);
  gemm_qkv<<<dim3(32, 8, 3), blk, 0, stream>>>(Abf, Wt, bq, bk, bv, Qp, Kp, Vt);
  flash_kernel<<<dim3(1024), blk, 0, stream>>>(Qp, Kp, Vt, AO);
  gemm_o<<<dim3(64, 8), blk, 0, stream>>>(AO, Wt + (size_t)3 * 1024 * 1024, bo, out);
}

// Round 5
// 132.757 us; speedup vs baseline: 1.1245x; 1.1245x over previous
//
#include <hip/hip_runtime.h>
#include <hip/hip_bf16.h>
#include <stdint.h>
#include <stddef.h>

// MHA fwd: B=2 S=2048 D=1024 H=16 DK=64.
// prep (W->Wt bf16 transpose + q/k/v fp32->bf16, one launch) -> gemm_qkv
// (pure-bf16 m97-style) -> flash (512 blocks, 4 waves x 32 q-rows, KVBLK=64,
// QUAD-buffered LDS, single barrier/iter, prefetch depth 2, swapped 32x32x16
// QK^T, exp2 softmax, pack+permlane32_swap) -> gemm_o (64x128).
//
// R5: R4's 2x2 kv-split regressed (73us): halved compute-per-barrier, doubled
// KV staging. Reverted to R3's flash structure (61us) and attacked the
// measured stall (both pipes <50%, ~4.6K cyc/iter wall vs ~600 active):
//  - quad-buffer (64KB LDS), ONE s_barrier per iter (was 2): waves may drift
//    a full iteration; buffer written at (t+2)&3 is 3 mod 4 away from the
//    slowest possible reader (t-1)&3.
//  - prefetch depth 2 (vmcnt(8)): loads get ~2 iterations of latency cover
//    instead of 1 (cold L2/HBM misses were blowing through depth-1).
// wt+cvt merged into one prep launch (saves a gap, overlaps two mem-bound
// streams). gemm_o kept at R4's 64x128 (2 blocks/CU).

typedef __bf16 bf16;
typedef __attribute__((ext_vector_type(4))) bf16 bf16x4;
typedef __attribute__((ext_vector_type(8))) bf16 bf16x8;
typedef __attribute__((ext_vector_type(4))) float f32x4;
typedef __attribute__((ext_vector_type(16))) float f32x16;
typedef __attribute__((ext_vector_type(2))) unsigned int uint2v;

#define DEVINL static __device__ __forceinline__

DEVINL void gload_lds16(const void* g, void* l) {
  __builtin_amdgcn_global_load_lds(
      (const __attribute__((address_space(1))) void*)g,
      (__attribute__((address_space(3))) void*)l, 16, 0, 0);
}

DEVINL f32x4 mfma16(bf16x8 a, bf16x8 b, f32x4 c) {
  return __builtin_amdgcn_mfma_f32_16x16x32_bf16(a, b, c, 0, 0, 0);
}
DEVINL f32x16 mfma32(bf16x8 a, bf16x8 b, f32x16 c) {
  return __builtin_amdgcn_mfma_f32_32x32x16_bf16(a, b, c, 0, 0, 0);
}
// v_exp_f32 computes 2^x; log2(e) is folded into the Q pre-scale.
DEVINL float fexp2(float x) {
  float r;
  asm("v_exp_f32 %0, %1" : "=v"(r) : "v"(x));
  return r;
}
// RNE f32->bf16 pair pack via compiler casts (m240: don't hand-write cvt_pk).
DEVINL unsigned pack2(float lo, float hi) {
  union { bf16 h[2]; unsigned u; } t;
  t.h[0] = (bf16)lo; t.h[1] = (bf16)hi;
  return t.u;
}
DEVINL bf16x8 mk8(unsigned a, unsigned b, unsigned c, unsigned d) {
  union { unsigned u[4]; bf16x8 v; } t;
  t.u[0] = a; t.u[1] = b; t.u[2] = c; t.u[3] = d;
  return t.v;
}

// ---------------------------------------------------------------------------
// Kernel 1: prep. blocks [0,6144): q/k/v fp32->bf16 streaming cvt.
//           blocks [6144,7168): W[k][n] fp32 -> Wt[t][n][k] bf16 transpose.
// ---------------------------------------------------------------------------
__global__ __launch_bounds__(256) void prep_kernel(
    const float* __restrict__ q, const float* __restrict__ k,
    const float* __restrict__ v,
    const float* __restrict__ w0, const float* __restrict__ w1,
    const float* __restrict__ w2, const float* __restrict__ w3,
    bf16* __restrict__ Abf, bf16* __restrict__ Wt) {
  __shared__ float tile[64 * 65];
  int bx = blockIdx.x;
  if (bx < 6144) {
    int z = bx >> 11, blk = bx & 2047;
    const float* src = (z == 0) ? q : (z == 1) ? k : v;
    size_t off = ((size_t)blk * 256 + threadIdx.x) * 8;
    f32x4 a = *(const f32x4*)(src + off);
    f32x4 b = *(const f32x4*)(src + off + 4);
    bf16x8 h;
#pragma unroll
    for (int j = 0; j < 4; ++j) { h[j] = (bf16)a[j]; h[4 + j] = (bf16)b[j]; }
    *(bf16x8*)(Abf + (size_t)z * 4194304 + off) = h;
  } else {
    int tb = bx - 6144;
    int t = tb >> 8;
    tb &= 255;
    const float* w = (t == 0) ? w0 : (t == 1) ? w1 : (t == 2) ? w2 : w3;
    bf16* o = Wt + (size_t)t * 1024 * 1024;
    int k0 = (tb >> 4) * 64, n0 = (tb & 15) * 64;
    int c = threadIdx.x & 63, r0 = threadIdx.x >> 6;
    for (int r = r0; r < 64; r += 4)
      tile[r * 65 + c] = w[(size_t)(k0 + r) * 1024 + n0 + c];
    __syncthreads();
    for (int r = r0; r < 64; r += 4)
      o[(size_t)(n0 + r) * 1024 + k0 + c] = (bf16)tile[c * 65 + r];
  }
}

// ---------------------------------------------------------------------------
// Kernel 2: QKV projection GEMM (pure bf16, m97 structure).
// Q scaled by 0.125*log2e in epilogue -> Qp; K -> Kp; V transposed -> Vt.
// ---------------------------------------------------------------------------
__global__ __launch_bounds__(256) void gemm_qkv(
    const bf16* __restrict__ Abf, const bf16* __restrict__ Wt,
    const float* __restrict__ bq, const float* __restrict__ bk,
    const float* __restrict__ bv,
    bf16* __restrict__ outQ, bf16* __restrict__ outK, bf16* __restrict__ Vt) {
  int z = blockIdx.z;
  const bf16* A    = Abf + (size_t)z * 4194304;
  const bf16* Wz   = Wt + (size_t)z * 1024 * 1024;
  const float* bia = (z == 0) ? bq : (z == 1) ? bk : bv;
  float scale      = (z == 0) ? 0.18033688011112042f : 1.0f;  // 0.125*log2(e)

  __shared__ bf16 As[2][128 * 32];
  __shared__ bf16 Bs[2][128 * 32];

  int m0 = blockIdx.x * 128, n0 = blockIdx.y * 128;
  int tid = threadIdx.x, w = tid >> 6, l = tid & 63;
  int wm = (w >> 1) * 64, wn = (w & 1) * 64;
  int c16 = l & 15, g = l >> 4;
  int rsw = (c16 >> 1) & 3;

  int brow0 = (w * 2 + 0) * 16 + (l >> 2);
  int brow1 = (w * 2 + 1) * 16 + (l >> 2);
  int bk0 = ((l & 3) ^ ((brow0 >> 1) & 3)) * 8;
  int bk1 = ((l & 3) ^ ((brow1 >> 1) & 3)) * 8;

  f32x4 acc[4][4] = {};

#define STAGE_QKV(buf, kt)                                                   \
  do {                                                                       \
    gload_lds16(A + (size_t)(m0 + brow0) * 1024 + (kt) + bk0,                \
                (char*)As[buf] + (w * 2 + 0) * 1024 + l * 16);               \
    gload_lds16(A + (size_t)(m0 + brow1) * 1024 + (kt) + bk1,                \
                (char*)As[buf] + (w * 2 + 1) * 1024 + l * 16);               \
    gload_lds16(Wz + (size_t)(n0 + brow0) * 1024 + (kt) + bk0,               \
                (char*)Bs[buf] + (w * 2 + 0) * 1024 + l * 16);               \
    gload_lds16(Wz + (size_t)(n0 + brow1) * 1024 + (kt) + bk1,               \
                (char*)Bs[buf] + (w * 2 + 1) * 1024 + l * 16);               \
  } while (0)

  STAGE_QKV(0, 0);
  __syncthreads();

  int cur = 0;
  for (int kt = 0; kt < 1024; kt += 32) {
    if (kt < 992) STAGE_QKV(cur ^ 1, kt + 32);
    bf16x8 af[4], bfr[4];
#pragma unroll
    for (int mt = 0; mt < 4; ++mt)
      af[mt] = *(const bf16x8*)&As[cur][(wm + mt * 16 + c16) * 32 + ((g ^ rsw) * 8)];
#pragma unroll
    for (int nt = 0; nt < 4; ++nt)
      bfr[nt] = *(const bf16x8*)&Bs[cur][(wn + nt * 16 + c16) * 32 + ((g ^ rsw) * 8)];
#pragma unroll
    for (int mt = 0; mt < 4; ++mt)
#pragma unroll
      for (int nt = 0; nt < 4; ++nt)
        acc[mt][nt] = mfma16(af[mt], bfr[nt], acc[mt][nt]);
    __syncthreads();  // drains vmcnt -> next buffer staged
    cur ^= 1;
  }
#undef STAGE_QKV

  if (z < 2) {
    bf16* Cout = (z == 0) ? outQ : outK;
#pragma unroll
    for (int mt = 0; mt < 4; ++mt)
#pragma unroll
      for (int nt = 0; nt < 4; ++nt) {
        int n = n0 + wn + nt * 16 + c16;
        float bb = bia[n];
#pragma unroll
        for (int r = 0; r < 4; ++r) {
          int m = m0 + wm + mt * 16 + g * 4 + r;
          Cout[(size_t)m * 1024 + n] = (bf16)((acc[mt][nt][r] + bb) * scale);
        }
      }
  } else {
    // V: write transposed -> Vt[(b*16+h)*64 + dk][s], 4 consecutive s per lane
#pragma unroll
    for (int mt = 0; mt < 4; ++mt)
#pragma unroll
      for (int nt = 0; nt < 4; ++nt) {
        int n = n0 + wn + nt * 16 + c16;       // h*64 + dk
        float bb = bia[n];
        int m = m0 + wm + mt * 16 + g * 4;     // b*2048 + s (4-aligned)
        int b = m >> 11, s = m & 2047;
        bf16x4 v;
#pragma unroll
        for (int r = 0; r < 4; ++r) v[r] = (bf16)(acc[mt][nt][r] + bb);
        *(bf16x4*)&Vt[((size_t)(b * 16 + (n >> 6)) * 64 + (n & 63)) * 2048 + s] = v;
      }
  }
}

// ---------------------------------------------------------------------------
// Kernel 3: flash attention. Block = (b,h,128 q-rows); 4 waves x 32 q-rows.
// KVBLK=64 staged in LDS (K [s][dk], Vt [dk][s]) QUAD-buffered, XOR-swizzled.
// Single s_barrier per iter, prefetch depth 2 (vmcnt(8)).
// Swapped QK^T (mfma32(K,Q)) -> P lane-local -> pack+permlane32_swap -> PV.
// Softmax uses 2^x directly (log2e folded into Q scale upstream).
// ---------------------------------------------------------------------------
__global__ __launch_bounds__(256) void flash_kernel(
    const bf16* __restrict__ Qp, const bf16* __restrict__ Kp,
    const bf16* __restrict__ Vt, bf16* __restrict__ AO) {
  __shared__ __align__(16) bf16 Ks[4][64 * 64];
  __shared__ __align__(16) bf16 Vs[4][64 * 64];

  int orig = blockIdx.x;
  int wg = (orig & 7) * 64 + (orig >> 3);   // XCD-chunked, bijective (512 % 8 == 0)
  int bh = wg >> 4, qb = wg & 15;
  int b = bh >> 4, h = bh & 15;
  int tid = threadIdx.x, w = tid >> 6, l = tid & 63;
  int lo5 = l & 31, g = l >> 5;
  int q0 = qb * 128 + w * 32;

  // Q as B-fragments: qf[kt] = Q[q0+lo5][kt*16 + g*8 + j]
  const bf16* qptr = Qp + (size_t)(b * 2048 + q0 + lo5) * 1024 + h * 64 + g * 8;
  bf16x8 qf0 = *(const bf16x8*)(qptr + 0);
  bf16x8 qf1 = *(const bf16x8*)(qptr + 16);
  bf16x8 qf2 = *(const bf16x8*)(qptr + 32);
  bf16x8 qf3 = *(const bf16x8*)(qptr + 48);

  const bf16* kbase = Kp + (size_t)(b * 2048) * 1024 + h * 64;
  const bf16* vbase = Vt + (size_t)bh * 64 * 2048;

  // staging indices: unit u in [0,512): row=u>>3, col unit c=u&7, source col c^(row&7)
  int u0 = w * 64 + l;
  int u1 = (4 + w) * 64 + l;
  int r0s = u0 >> 3, c0s = (u0 & 7) ^ (r0s & 7);
  int r1s = u1 >> 3, c1s = (u1 & 7) ^ (r1s & 7);

#define STAGE(buf, s0)                                                          \
  do {                                                                          \
    gload_lds16(kbase + (size_t)((s0) + r0s) * 1024 + c0s * 8,                  \
                (bf16*)Ks[buf] + u0 * 8);                                       \
    gload_lds16(kbase + (size_t)((s0) + r1s) * 1024 + c1s * 8,                  \
                (bf16*)Ks[buf] + u1 * 8);                                       \
    gload_lds16(vbase + (size_t)r0s * 2048 + (s0) + c0s * 8,                    \
                (bf16*)Vs[buf] + u0 * 8);                                       \
    gload_lds16(vbase + (size_t)r1s * 2048 + (s0) + c1s * 8,                    \
                (bf16*)Vs[buf] + u1 * 8);                                       \
  } while (0)

#define LDSK(cp, nt, kt) \
  (*(const bf16x8*)&cp[(((nt)*32 + lo5) << 6) + (((((kt)*2 + g)) ^ (lo5 & 7)) << 3)])
#define LDSV(cp, dt, st) \
  (*(const bf16x8*)&cp[(((dt)*32 + lo5) << 6) + (((((st)*2 + g)) ^ (lo5 & 7)) << 3)])

  f32x16 o0 = {}, o1 = {};
  float ps0 = 0.f, ps1 = 0.f, ps2 = 0.f, ps3 = 0.f;

  STAGE(0, 0);
  STAGE(1, 64);
  for (int t = 0; t < 32; ++t) {
    if (t < 30) {
      STAGE((t + 2) & 3, (t + 2) * 64);
      asm volatile("s_waitcnt vmcnt(8)" ::: "memory");   // tile t landed
    } else if (t == 30) {
      asm volatile("s_waitcnt vmcnt(4)" ::: "memory");
    } else {
      asm volatile("s_waitcnt vmcnt(0)" ::: "memory");
    }
    __builtin_amdgcn_s_barrier();        // all waves' quarters of tile t landed
    __builtin_amdgcn_sched_barrier(0);
    const bf16* kc = Ks[t & 3];
    const bf16* vc = Vs[t & 3];

    // ---- S^T tile 0 (k_local 0..31; row=k, col=q=lo5) ----
    f32x16 sv = {};
    __builtin_amdgcn_s_setprio(1);
    sv = mfma32(LDSK(kc, 0, 0), qf0, sv);
    sv = mfma32(LDSK(kc, 0, 1), qf1, sv);
    sv = mfma32(LDSK(kc, 0, 2), qf2, sv);
    sv = mfma32(LDSK(kc, 0, 3), qf3, sv);
    __builtin_amdgcn_s_setprio(0);
    float p[16];
#pragma unroll
    for (int r = 0; r < 16; ++r) p[r] = fexp2(sv[r]);
    ps0 += p[0] + p[4] + p[8] + p[12];
    ps1 += p[1] + p[5] + p[9] + p[13];
    ps2 += p[2] + p[6] + p[10] + p[14];
    ps3 += p[3] + p[7] + p[11] + p[15];
    unsigned pw0 = pack2(p[0], p[1]), pw1 = pack2(p[2], p[3]);
    unsigned pw2 = pack2(p[4], p[5]), pw3 = pack2(p[6], p[7]);
    unsigned pw4 = pack2(p[8], p[9]), pw5 = pack2(p[10], p[11]);
    unsigned pw6 = pack2(p[12], p[13]), pw7 = pack2(p[14], p[15]);
    uint2v a02 = __builtin_amdgcn_permlane32_swap(pw0, pw2, false, false);
    uint2v a13 = __builtin_amdgcn_permlane32_swap(pw1, pw3, false, false);
    uint2v a46 = __builtin_amdgcn_permlane32_swap(pw4, pw6, false, false);
    uint2v a57 = __builtin_amdgcn_permlane32_swap(pw5, pw7, false, false);
    bf16x8 pa0 = mk8(a02.x, a13.x, a02.y, a13.y);  // s 0..15
    bf16x8 pa1 = mk8(a46.x, a57.x, a46.y, a57.y);  // s 16..31

    // ---- S^T tile 1 (k_local 32..63) ----
    f32x16 sw = {};
    __builtin_amdgcn_s_setprio(1);
    sw = mfma32(LDSK(kc, 1, 0), qf0, sw);
    sw = mfma32(LDSK(kc, 1, 1), qf1, sw);
    sw = mfma32(LDSK(kc, 1, 2), qf2, sw);
    sw = mfma32(LDSK(kc, 1, 3), qf3, sw);
    __builtin_amdgcn_s_setprio(0);
#pragma unroll
    for (int r = 0; r < 16; ++r) p[r] = fexp2(sw[r]);
    ps0 += p[0] + p[4] + p[8] + p[12];
    ps1 += p[1] + p[5] + p[9] + p[13];
    ps2 += p[2] + p[6] + p[10] + p[14];
    ps3 += p[3] + p[7] + p[11] + p[15];
    pw0 = pack2(p[0], p[1]); pw1 = pack2(p[2], p[3]);
    pw2 = pack2(p[4], p[5]); pw3 = pack2(p[6], p[7]);
    pw4 = pack2(p[8], p[9]); pw5 = pack2(p[10], p[11]);
    pw6 = pack2(p[12], p[13]); pw7 = pack2(p[14], p[15]);
    a02 = __builtin_amdgcn_permlane32_swap(pw0, pw2, false, false);
    a13 = __builtin_amdgcn_permlane32_swap(pw1, pw3, false, false);
    a46 = __builtin_amdgcn_permlane32_swap(pw4, pw6, false, false);
    a57 = __builtin_amdgcn_permlane32_swap(pw5, pw7, false, false);
    bf16x8 pb0 = mk8(a02.x, a13.x, a02.y, a13.y);  // s 32..47
    bf16x8 pb1 = mk8(a46.x, a57.x, a46.y, a57.y);  // s 48..63

    // ---- O += P V ----
    __builtin_amdgcn_s_setprio(1);
    o0 = mfma32(pa0, LDSV(vc, 0, 0), o0);
    o1 = mfma32(pa0, LDSV(vc, 1, 0), o1);
    o0 = mfma32(pa1, LDSV(vc, 0, 1), o0);
    o1 = mfma32(pa1, LDSV(vc, 1, 1), o1);
    o0 = mfma32(pb0, LDSV(vc, 0, 2), o0);
    o1 = mfma32(pb0, LDSV(vc, 1, 2), o1);
    o0 = mfma32(pb1, LDSV(vc, 0, 3), o0);
    o1 = mfma32(pb1, LDSV(vc, 1, 3), o1);
    __builtin_amdgcn_s_setprio(0);
    // no trailing barrier: quad-buffer makes (t+2)&3 safe vs slowest reader
  }
#undef STAGE
#undef LDSK
#undef LDSV

  // tot on lane l = softmax denominator for q = q0 + (l&31)
  float plsum = (ps0 + ps1) + (ps2 + ps3);
  float tot = plsum + __shfl_xor(plsum, 32);

#pragma unroll
  for (int r = 0; r < 16; ++r) {
    int qr = (r & 3) + 8 * (r >> 2) + 4 * g;        // output row of o0[r]/o1[r]
    float inv = 1.0f / __shfl(tot, qr);             // row qr's denominator
    bf16* op = AO + (size_t)(b * 2048 + q0 + qr) * 1024 + h * 64 + lo5;
    op[0]  = (bf16)(o0[r] * inv);
    op[32] = (bf16)(o1[r] * inv);
  }
}

// ---------------------------------------------------------------------------
// Kernel 4: output projection, 64x128 tile (512 blocks = 2/CU), m97 structure,
// swizzled LDS. fp32 out + bias.
// ---------------------------------------------------------------------------
__global__ __launch_bounds__(256) void gemm_o(
    const bf16* __restrict__ A, const bf16* __restrict__ Wt3,
    const float* __restrict__ bo, float* __restrict__ C) {
  __shared__ bf16 As[2][64 * 32];
  __shared__ bf16 Bs[2][128 * 32];
  int m0 = blockIdx.x * 64, n0 = blockIdx.y * 128;
  int tid = threadIdx.x, w = tid >> 6, l = tid & 63;
  int wm = (w >> 1) * 32, wn = (w & 1) * 64;
  int c16 = l & 15, g = l >> 4;
  int rsw = (c16 >> 1) & 3;

  // A staging: 1 chunk/lane. row = tid>>2, phys chunk = tid&3
  int arow = tid >> 2, akc = tid & 3;
  int asrc = (akc ^ ((arow >> 1) & 3)) * 8;
  // B staging: 2 chunks/lane
  int brow0 = (w * 2 + 0) * 16 + (l >> 2);
  int brow1 = (w * 2 + 1) * 16 + (l >> 2);
  int bk0 = ((l & 3) ^ ((brow0 >> 1) & 3)) * 8;
  int bk1 = ((l & 3) ^ ((brow1 >> 1) & 3)) * 8;

  f32x4 acc[2][4] = {};

#define STAGE_O(buf, kt)                                                     \
  do {                                                                       \
    gload_lds16(A + (size_t)(m0 + arow) * 1024 + (kt) + asrc,                \
                (char*)As[buf] + tid * 16);                                  \
    gload_lds16(Wt3 + (size_t)(n0 + brow0) * 1024 + (kt) + bk0,              \
                (char*)Bs[buf] + (w * 2 + 0) * 1024 + l * 16);               \
    gload_lds16(Wt3 + (size_t)(n0 + brow1) * 1024 + (kt) + bk1,              \
                (char*)Bs[buf] + (w * 2 + 1) * 1024 + l * 16);               \
  } while (0)

  STAGE_O(0, 0);
  __syncthreads();

  int cur = 0;
  for (int kt = 0; kt < 1024; kt += 32) {
    if (kt < 992) STAGE_O(cur ^ 1, kt + 32);
    bf16x8 af[2], bfr[4];
#pragma unroll
    for (int mt = 0; mt < 2; ++mt)
      af[mt] = *(const bf16x8*)&As[cur][(wm + mt * 16 + c16) * 32 + ((g ^ rsw) * 8)];
#pragma unroll
    for (int nt = 0; nt < 4; ++nt)
      bfr[nt] = *(const bf16x8*)&Bs[cur][(wn + nt * 16 + c16) * 32 + ((g ^ rsw) * 8)];
#pragma unroll
    for (int mt = 0; mt < 2; ++mt)
#pragma unroll
      for (int nt = 0; nt < 4; ++nt)
        acc[mt][nt] = mfma16(af[mt], bfr[nt], acc[mt][nt]);
    __syncthreads();  // drains vmcnt -> next buffer staged
    cur ^= 1;
  }
#undef STAGE_O

#pragma unroll
  for (int mt = 0; mt < 2; ++mt)
#pragma unroll
    for (int nt = 0; nt < 4; ++nt) {
      int n = n0 + wn + nt * 16 + c16;
      float bb = bo[n];
#pragma unroll
      for (int r = 0; r < 4; ++r) {
        int m = m0 + wm + mt * 16 + g * 4 + r;
        C[(size_t)m * 1024 + n] = acc[mt][nt][r] + bb;
      }
    }
}

// ---------------------------------------------------------------------------
extern "C" void kernel_launch(void* const* d_in, const int* in_sizes, int n_in,
                              void* d_out, int out_size, void* d_ws, size_t ws_size,
                              hipStream_t stream) {
  const float* query = (const float*)d_in[0];
  const float* key_  = (const float*)d_in[1];
  const float* value = (const float*)d_in[2];
  const float* Wq = (const float*)d_in[3];
  const float* bq = (const float*)d_in[4];
  const float* Wk = (const float*)d_in[5];
  const float* bk = (const float*)d_in[6];
  const float* Wv = (const float*)d_in[7];
  const float* bv = (const float*)d_in[8];
  const float* Wo = (const float*)d_in[9];
  const float* bo = (const float*)d_in[10];
  float* out = (float*)d_out;

  char* ws = (char*)d_ws;
  const size_t MB = 1024 * 1024;
  bf16* Wt  = (bf16*)(ws);              // 4 x [1024][1024] bf16 = 8 MB
  bf16* Abf = (bf16*)(ws + 8 * MB);     // 3 x [4096][1024] bf16 = 24 MB
  bf16* Qp  = (bf16*)(ws + 32 * MB);    // [4096][1024] bf16 (pre-scaled)
  bf16* Kp  = (bf16*)(ws + 40 * MB);    // [4096][1024]
  bf16* Vt  = (bf16*)(ws + 48 * MB);    // [32][64][2048]
  bf16* AO  = (bf16*)(ws + 8 * MB);     // attn out [4096][1024] (reuses Abf)

  dim3 blk(256);
  prep_kernel<<<dim3(7168), blk, 0, stream>>>(query, key_, value,
                                              Wq, Wk, Wv, Wo, Abf, Wt);
  gemm_qkv<<<dim3(32, 8, 3), blk, 0, stream>>>(Abf, Wt, bq, bk, bv, Qp, Kp, Vt);
  flash_kernel<<<dim3(512), blk, 0, stream>>>(Qp, Kp, Vt, AO);
  gemm_o<<<dim3(64, 8), blk, 0, stream>>>(AO, Wt + (size_t)3 * 1024 * 1024, bo, out);
}

// Round 6
// 131.866 us; speedup vs baseline: 1.1321x; 1.0068x over previous
//
#include <hip/hip_runtime.h>
#include <hip/hip_bf16.h>
#include <stdint.h>
#include <stddef.h>

// MHA fwd: B=2 S=2048 D=1024 H=16 DK=64.
// wt (W->Wt bf16 transpose) -> gemm_qkv (fp32-A staged via global_load_lds
// with 8-chunk XOR swizzle, in-reg cvt to bf16 fragments; B bf16; m97
// barrier structure) -> flash (512 blocks, 4 waves x 32 q-rows, KVBLK=64,
// quad-buffered LDS, 1 barrier/iter, both QK^T clusters issued before
// softmax) -> gemm_o (64x128).
//
// R6: R5 flash pipelining = NULL (61.3 vs 61.0) -> flash is not
// barrier/prefetch-bound; leave structure, only hoist QK1 mfmas above SM0
// so their latency hides under exp/pack VALU. Attack the 71.5us non-flash
// tail instead: the cvt pass was a 72MB materialization round-trip
// (write Abf, re-read it). gemm_qkv now stages fp32 A directly through
// global_load_lds (async DMA - NOT R2's reg-staging trap) into a swizzled
// fp32 LDS tile and converts after ds_read (16 cvt_pk/iter). prep shrinks
// to W-transpose only. Saves ~72MB traffic + a launch.

typedef __bf16 bf16;
typedef __attribute__((ext_vector_type(4))) bf16 bf16x4;
typedef __attribute__((ext_vector_type(8))) bf16 bf16x8;
typedef __attribute__((ext_vector_type(4))) float f32x4;
typedef __attribute__((ext_vector_type(16))) float f32x16;
typedef __attribute__((ext_vector_type(2))) unsigned int uint2v;

#define DEVINL static __device__ __forceinline__

DEVINL void gload_lds16(const void* g, void* l) {
  __builtin_amdgcn_global_load_lds(
      (const __attribute__((address_space(1))) void*)g,
      (__attribute__((address_space(3))) void*)l, 16, 0, 0);
}

DEVINL f32x4 mfma16(bf16x8 a, bf16x8 b, f32x4 c) {
  return __builtin_amdgcn_mfma_f32_16x16x32_bf16(a, b, c, 0, 0, 0);
}
DEVINL f32x16 mfma32(bf16x8 a, bf16x8 b, f32x16 c) {
  return __builtin_amdgcn_mfma_f32_32x32x16_bf16(a, b, c, 0, 0, 0);
}
// v_exp_f32 computes 2^x; log2(e) is folded into the Q pre-scale.
DEVINL float fexp2(float x) {
  float r;
  asm("v_exp_f32 %0, %1" : "=v"(r) : "v"(x));
  return r;
}
// RNE f32->bf16 pair pack via compiler casts (m240: don't hand-write cvt_pk).
DEVINL unsigned pack2(float lo, float hi) {
  union { bf16 h[2]; unsigned u; } t;
  t.h[0] = (bf16)lo; t.h[1] = (bf16)hi;
  return t.u;
}
DEVINL bf16x8 mk8(unsigned a, unsigned b, unsigned c, unsigned d) {
  union { unsigned u[4]; bf16x8 v; } t;
  t.u[0] = a; t.u[1] = b; t.u[2] = c; t.u[3] = d;
  return t.v;
}

// ---------------------------------------------------------------------------
// Kernel 1: weight transpose+convert. W[k][n] fp32 -> Wt[t][n][k] bf16
// ---------------------------------------------------------------------------
__global__ __launch_bounds__(256) void wt_kernel(
    const float* __restrict__ w0, const float* __restrict__ w1,
    const float* __restrict__ w2, const float* __restrict__ w3,
    bf16* __restrict__ out) {
  __shared__ float tile[64 * 65];
  int t = blockIdx.y;
  const float* w = (t == 0) ? w0 : (t == 1) ? w1 : (t == 2) ? w2 : w3;
  bf16* o = out + (size_t)t * 1024 * 1024;
  int tb = blockIdx.x;
  int k0 = (tb >> 4) * 64, n0 = (tb & 15) * 64;
  int c = threadIdx.x & 63, r0 = threadIdx.x >> 6;
  for (int r = r0; r < 64; r += 4)
    tile[r * 65 + c] = w[(size_t)(k0 + r) * 1024 + n0 + c];
  __syncthreads();
  for (int r = r0; r < 64; r += 4)
    o[(size_t)(n0 + r) * 1024 + k0 + c] = (bf16)tile[c * 65 + r];
}

// ---------------------------------------------------------------------------
// Kernel 2: QKV projection GEMM. A = fp32 input staged via global_load_lds
// into swizzled fp32 LDS tile (8 chunks/row, chunk ^= row&7), converted to
// bf16 fragments in-register after ds_read. B = bf16 Wt (old path).
// Q scaled by 0.125*log2e in epilogue -> Qp; K -> Kp; V transposed -> Vt.
// ---------------------------------------------------------------------------
__global__ __launch_bounds__(256) void gemm_qkv(
    const float* __restrict__ Aq, const float* __restrict__ Ak,
    const float* __restrict__ Av, const bf16* __restrict__ Wt,
    const float* __restrict__ bq, const float* __restrict__ bk,
    const float* __restrict__ bv,
    bf16* __restrict__ outQ, bf16* __restrict__ outK, bf16* __restrict__ Vt) {
  int z = blockIdx.z;
  const float* A   = (z == 0) ? Aq : (z == 1) ? Ak : Av;
  const bf16* Wz   = Wt + (size_t)z * 1024 * 1024;
  const float* bia = (z == 0) ? bq : (z == 1) ? bk : bv;
  float scale      = (z == 0) ? 0.18033688011112042f : 1.0f;  // 0.125*log2(e)

  __shared__ float Af[2][128 * 32];   // fp32 A tile, 16KB each
  __shared__ bf16  Bs[2][128 * 32];   // bf16 B tile, 8KB each

  int m0 = blockIdx.x * 128, n0 = blockIdx.y * 128;
  int tid = threadIdx.x, w = tid >> 6, l = tid & 63;
  int wm = (w >> 1) * 64, wn = (w & 1) * 64;
  int c16 = l & 15, g = l >> 4;
  int rsw = (c16 >> 1) & 3;           // B read-side swizzle (unchanged)

  // A staging: 1024 16B-units; unit u: row=u>>3, phys chunk=u&7,
  // logical source chunk = (u&7)^(row&7). 4 units/thread.
  int ua[4], arow[4], asrc[4];
#pragma unroll
  for (int i = 0; i < 4; ++i) {
    ua[i] = (w * 4 + i) * 64 + l;
    arow[i] = ua[i] >> 3;
    asrc[i] = ((ua[i] & 7) ^ (arow[i] & 7)) * 4;  // float offset within row
  }
  // B staging: 2 units/thread, pre-swizzled global k-chunk (unchanged)
  int brow0 = (w * 2 + 0) * 16 + (l >> 2);
  int brow1 = (w * 2 + 1) * 16 + (l >> 2);
  int bk0 = ((l & 3) ^ ((brow0 >> 1) & 3)) * 8;
  int bk1 = ((l & 3) ^ ((brow1 >> 1) & 3)) * 8;

  f32x4 acc[4][4] = {};

#define STAGE_QKV(buf, kt)                                                   \
  do {                                                                       \
    _Pragma("unroll") for (int i = 0; i < 4; ++i)                            \
      gload_lds16(A + (size_t)(m0 + arow[i]) * 1024 + (kt) + asrc[i],        \
                  (char*)Af[buf] + ua[i] * 16);                              \
    gload_lds16(Wz + (size_t)(n0 + brow0) * 1024 + (kt) + bk0,               \
                (char*)Bs[buf] + (w * 2 + 0) * 1024 + l * 16);               \
    gload_lds16(Wz + (size_t)(n0 + brow1) * 1024 + (kt) + bk1,               \
                (char*)Bs[buf] + (w * 2 + 1) * 1024 + l * 16);               \
  } while (0)

  STAGE_QKV(0, 0);
  __syncthreads();

  int cur = 0;
  for (int kt = 0; kt < 1024; kt += 32) {
    if (kt < 992) STAGE_QKV(cur ^ 1, kt + 32);
    bf16x8 af[4], bfr[4];
#pragma unroll
    for (int mt = 0; mt < 4; ++mt) {
      int row = wm + mt * 16 + c16;
      int r7 = row & 7;
      f32x4 lo = *(const f32x4*)&Af[cur][row * 32 + (((2 * g)     ^ r7) << 2)];
      f32x4 hi = *(const f32x4*)&Af[cur][row * 32 + (((2 * g + 1) ^ r7) << 2)];
      bf16x8 h;
#pragma unroll
      for (int j = 0; j < 4; ++j) { h[j] = (bf16)lo[j]; h[4 + j] = (bf16)hi[j]; }
      af[mt] = h;
    }
#pragma unroll
    for (int nt = 0; nt < 4; ++nt)
      bfr[nt] = *(const bf16x8*)&Bs[cur][(wn + nt * 16 + c16) * 32 + ((g ^ rsw) * 8)];
#pragma unroll
    for (int mt = 0; mt < 4; ++mt)
#pragma unroll
      for (int nt = 0; nt < 4; ++nt)
        acc[mt][nt] = mfma16(af[mt], bfr[nt], acc[mt][nt]);
    __syncthreads();  // drains vmcnt -> next buffer staged
    cur ^= 1;
  }
#undef STAGE_QKV

  if (z < 2) {
    bf16* Cout = (z == 0) ? outQ : outK;
#pragma unroll
    for (int mt = 0; mt < 4; ++mt)
#pragma unroll
      for (int nt = 0; nt < 4; ++nt) {
        int n = n0 + wn + nt * 16 + c16;
        float bb = bia[n];
#pragma unroll
        for (int r = 0; r < 4; ++r) {
          int m = m0 + wm + mt * 16 + g * 4 + r;
          Cout[(size_t)m * 1024 + n] = (bf16)((acc[mt][nt][r] + bb) * scale);
        }
      }
  } else {
    // V: write transposed -> Vt[(b*16+h)*64 + dk][s], 4 consecutive s per lane
#pragma unroll
    for (int mt = 0; mt < 4; ++mt)
#pragma unroll
      for (int nt = 0; nt < 4; ++nt) {
        int n = n0 + wn + nt * 16 + c16;       // h*64 + dk
        float bb = bia[n];
        int m = m0 + wm + mt * 16 + g * 4;     // b*2048 + s (4-aligned)
        int b = m >> 11, s = m & 2047;
        bf16x4 v;
#pragma unroll
        for (int r = 0; r < 4; ++r) v[r] = (bf16)(acc[mt][nt][r] + bb);
        *(bf16x4*)&Vt[((size_t)(b * 16 + (n >> 6)) * 64 + (n & 63)) * 2048 + s] = v;
      }
  }
}

// ---------------------------------------------------------------------------
// Kernel 3: flash attention. Block = (b,h,128 q-rows); 4 waves x 32 q-rows.
// KVBLK=64 staged in LDS (K [s][dk], Vt [dk][s]) QUAD-buffered, XOR-swizzled.
// Single s_barrier per iter, prefetch depth 2 (vmcnt(8)).
// Both QK^T clusters issued before softmax (MFMA latency hides under VALU).
// Swapped QK^T (mfma32(K,Q)) -> P lane-local -> pack+permlane32_swap -> PV.
// Softmax uses 2^x directly (log2e folded into Q scale upstream).
// ---------------------------------------------------------------------------
__global__ __launch_bounds__(256) void flash_kernel(
    const bf16* __restrict__ Qp, const bf16* __restrict__ Kp,
    const bf16* __restrict__ Vt, bf16* __restrict__ AO) {
  __shared__ __align__(16) bf16 Ks[4][64 * 64];
  __shared__ __align__(16) bf16 Vs[4][64 * 64];

  int orig = blockIdx.x;
  int wg = (orig & 7) * 64 + (orig >> 3);   // XCD-chunked, bijective (512 % 8 == 0)
  int bh = wg >> 4, qb = wg & 15;
  int b = bh >> 4, h = bh & 15;
  int tid = threadIdx.x, w = tid >> 6, l = tid & 63;
  int lo5 = l & 31, g = l >> 5;
  int q0 = qb * 128 + w * 32;

  // Q as B-fragments: qf[kt] = Q[q0+lo5][kt*16 + g*8 + j]
  const bf16* qptr = Qp + (size_t)(b * 2048 + q0 + lo5) * 1024 + h * 64 + g * 8;
  bf16x8 qf0 = *(const bf16x8*)(qptr + 0);
  bf16x8 qf1 = *(const bf16x8*)(qptr + 16);
  bf16x8 qf2 = *(const bf16x8*)(qptr + 32);
  bf16x8 qf3 = *(const bf16x8*)(qptr + 48);

  const bf16* kbase = Kp + (size_t)(b * 2048) * 1024 + h * 64;
  const bf16* vbase = Vt + (size_t)bh * 64 * 2048;

  // staging indices: unit u in [0,512): row=u>>3, col unit c=u&7, source col c^(row&7)
  int u0 = w * 64 + l;
  int u1 = (4 + w) * 64 + l;
  int r0s = u0 >> 3, c0s = (u0 & 7) ^ (r0s & 7);
  int r1s = u1 >> 3, c1s = (u1 & 7) ^ (r1s & 7);

#define STAGE(buf, s0)                                                          \
  do {                                                                          \
    gload_lds16(kbase + (size_t)((s0) + r0s) * 1024 + c0s * 8,                  \
                (bf16*)Ks[buf] + u0 * 8);                                       \
    gload_lds16(kbase + (size_t)((s0) + r1s) * 1024 + c1s * 8,                  \
                (bf16*)Ks[buf] + u1 * 8);                                       \
    gload_lds16(vbase + (size_t)r0s * 2048 + (s0) + c0s * 8,                    \
                (bf16*)Vs[buf] + u0 * 8);                                       \
    gload_lds16(vbase + (size_t)r1s * 2048 + (s0) + c1s * 8,                    \
                (bf16*)Vs[buf] + u1 * 8);                                       \
  } while (0)

#define LDSK(cp, nt, kt) \
  (*(const bf16x8*)&cp[(((nt)*32 + lo5) << 6) + (((((kt)*2 + g)) ^ (lo5 & 7)) << 3)])
#define LDSV(cp, dt, st) \
  (*(const bf16x8*)&cp[(((dt)*32 + lo5) << 6) + (((((st)*2 + g)) ^ (lo5 & 7)) << 3)])

  f32x16 o0 = {}, o1 = {};
  float ps0 = 0.f, ps1 = 0.f, ps2 = 0.f, ps3 = 0.f;

  STAGE(0, 0);
  STAGE(1, 64);
  for (int t = 0; t < 32; ++t) {
    if (t < 30) {
      STAGE((t + 2) & 3, (t + 2) * 64);
      asm volatile("s_waitcnt vmcnt(8)" ::: "memory");   // tile t landed
    } else if (t == 30) {
      asm volatile("s_waitcnt vmcnt(4)" ::: "memory");
    } else {
      asm volatile("s_waitcnt vmcnt(0)" ::: "memory");
    }
    __builtin_amdgcn_s_barrier();        // all waves' quarters of tile t landed
    __builtin_amdgcn_sched_barrier(0);
    const bf16* kc = Ks[t & 3];
    const bf16* vc = Vs[t & 3];

    // ---- both S^T tiles first: tile1's MFMA latency hides under SM0 ----
    f32x16 sv = {}, sw = {};
    __builtin_amdgcn_s_setprio(1);
    sv = mfma32(LDSK(kc, 0, 0), qf0, sv);
    sv = mfma32(LDSK(kc, 0, 1), qf1, sv);
    sv = mfma32(LDSK(kc, 0, 2), qf2, sv);
    sv = mfma32(LDSK(kc, 0, 3), qf3, sv);
    sw = mfma32(LDSK(kc, 1, 0), qf0, sw);
    sw = mfma32(LDSK(kc, 1, 1), qf1, sw);
    sw = mfma32(LDSK(kc, 1, 2), qf2, sw);
    sw = mfma32(LDSK(kc, 1, 3), qf3, sw);
    __builtin_amdgcn_s_setprio(0);

    // ---- softmax tile 0 (k_local 0..31; row=k, col=q=lo5) ----
    float p[16];
#pragma unroll
    for (int r = 0; r < 16; ++r) p[r] = fexp2(sv[r]);
    ps0 += p[0] + p[4] + p[8] + p[12];
    ps1 += p[1] + p[5] + p[9] + p[13];
    ps2 += p[2] + p[6] + p[10] + p[14];
    ps3 += p[3] + p[7] + p[11] + p[15];
    unsigned pw0 = pack2(p[0], p[1]), pw1 = pack2(p[2], p[3]);
    unsigned pw2 = pack2(p[4], p[5]), pw3 = pack2(p[6], p[7]);
    unsigned pw4 = pack2(p[8], p[9]), pw5 = pack2(p[10], p[11]);
    unsigned pw6 = pack2(p[12], p[13]), pw7 = pack2(p[14], p[15]);
    uint2v a02 = __builtin_amdgcn_permlane32_swap(pw0, pw2, false, false);
    uint2v a13 = __builtin_amdgcn_permlane32_swap(pw1, pw3, false, false);
    uint2v a46 = __builtin_amdgcn_permlane32_swap(pw4, pw6, false, false);
    uint2v a57 = __builtin_amdgcn_permlane32_swap(pw5, pw7, false, false);
    bf16x8 pa0 = mk8(a02.x, a13.x, a02.y, a13.y);  // s 0..15
    bf16x8 pa1 = mk8(a46.x, a57.x, a46.y, a57.y);  // s 16..31

    // ---- softmax tile 1 (k_local 32..63) ----
#pragma unroll
    for (int r = 0; r < 16; ++r) p[r] = fexp2(sw[r]);
    ps0 += p[0] + p[4] + p[8] + p[12];
    ps1 += p[1] + p[5] + p[9] + p[13];
    ps2 += p[2] + p[6] + p[10] + p[14];
    ps3 += p[3] + p[7] + p[11] + p[15];
    pw0 = pack2(p[0], p[1]); pw1 = pack2(p[2], p[3]);
    pw2 = pack2(p[4], p[5]); pw3 = pack2(p[6], p[7]);
    pw4 = pack2(p[8], p[9]); pw5 = pack2(p[10], p[11]);
    pw6 = pack2(p[12], p[13]); pw7 = pack2(p[14], p[15]);
    a02 = __builtin_amdgcn_permlane32_swap(pw0, pw2, false, false);
    a13 = __builtin_amdgcn_permlane32_swap(pw1, pw3, false, false);
    a46 = __builtin_amdgcn_permlane32_swap(pw4, pw6, false, false);
    a57 = __builtin_amdgcn_permlane32_swap(pw5, pw7, false, false);
    bf16x8 pb0 = mk8(a02.x, a13.x, a02.y, a13.y);  // s 32..47
    bf16x8 pb1 = mk8(a46.x, a57.x, a46.y, a57.y);  // s 48..63

    // ---- O += P V ----
    __builtin_amdgcn_s_setprio(1);
    o0 = mfma32(pa0, LDSV(vc, 0, 0), o0);
    o1 = mfma32(pa0, LDSV(vc, 1, 0), o1);
    o0 = mfma32(pa1, LDSV(vc, 0, 1), o0);
    o1 = mfma32(pa1, LDSV(vc, 1, 1), o1);
    o0 = mfma32(pb0, LDSV(vc, 0, 2), o0);
    o1 = mfma32(pb0, LDSV(vc, 1, 2), o1);
    o0 = mfma32(pb1, LDSV(vc, 0, 3), o0);
    o1 = mfma32(pb1, LDSV(vc, 1, 3), o1);
    __builtin_amdgcn_s_setprio(0);
    __builtin_amdgcn_sched_barrier(0);
    // no trailing barrier: quad-buffer makes (t+2)&3 safe vs slowest reader
  }
#undef STAGE
#undef LDSK
#undef LDSV

  // tot on lane l = softmax denominator for q = q0 + (l&31)
  float plsum = (ps0 + ps1) + (ps2 + ps3);
  float tot = plsum + __shfl_xor(plsum, 32);

#pragma unroll
  for (int r = 0; r < 16; ++r) {
    int qr = (r & 3) + 8 * (r >> 2) + 4 * g;        // output row of o0[r]/o1[r]
    float inv = 1.0f / __shfl(tot, qr);             // row qr's denominator
    bf16* op = AO + (size_t)(b * 2048 + q0 + qr) * 1024 + h * 64 + lo5;
    op[0]  = (bf16)(o0[r] * inv);
    op[32] = (bf16)(o1[r] * inv);
  }
}

// ---------------------------------------------------------------------------
// Kernel 4: output projection, 64x128 tile (512 blocks = 2/CU), m97 structure,
// swizzled LDS. fp32 out + bias.
// ---------------------------------------------------------------------------
__global__ __launch_bounds__(256) void gemm_o(
    const bf16* __restrict__ A, const bf16* __restrict__ Wt3,
    const float* __restrict__ bo, float* __restrict__ C) {
  __shared__ bf16 As[2][64 * 32];
  __shared__ bf16 Bs[2][128 * 32];
  int m0 = blockIdx.x * 64, n0 = blockIdx.y * 128;
  int tid = threadIdx.x, w = tid >> 6, l = tid & 63;
  int wm = (w >> 1) * 32, wn = (w & 1) * 64;
  int c16 = l & 15, g = l >> 4;
  int rsw = (c16 >> 1) & 3;

  // A staging: 1 chunk/lane. row = tid>>2, phys chunk = tid&3
  int arow = tid >> 2, akc = tid & 3;
  int asrc = (akc ^ ((arow >> 1) & 3)) * 8;
  // B staging: 2 chunks/lane
  int brow0 = (w * 2 + 0) * 16 + (l >> 2);
  int brow1 = (w * 2 + 1) * 16 + (l >> 2);
  int bk0 = ((l & 3) ^ ((brow0 >> 1) & 3)) * 8;
  int bk1 = ((l & 3) ^ ((brow1 >> 1) & 3)) * 8;

  f32x4 acc[2][4] = {};

#define STAGE_O(buf, kt)                                                     \
  do {                                                                       \
    gload_lds16(A + (size_t)(m0 + arow) * 1024 + (kt) + asrc,                \
                (char*)As[buf] + tid * 16);                                  \
    gload_lds16(Wt3 + (size_t)(n0 + brow0) * 1024 + (kt) + bk0,              \
                (char*)Bs[buf] + (w * 2 + 0) * 1024 + l * 16);               \
    gload_lds16(Wt3 + (size_t)(n0 + brow1) * 1024 + (kt) + bk1,              \
                (char*)Bs[buf] + (w * 2 + 1) * 1024 + l * 16);               \
  } while (0)

  STAGE_O(0, 0);
  __syncthreads();

  int cur = 0;
  for (int kt = 0; kt < 1024; kt += 32) {
    if (kt < 992) STAGE_O(cur ^ 1, kt + 32);
    bf16x8 af[2], bfr[4];
#pragma unroll
    for (int mt = 0; mt < 2; ++mt)
      af[mt] = *(const bf16x8*)&As[cur][(wm + mt * 16 + c16) * 32 + ((g ^ rsw) * 8)];
#pragma unroll
    for (int nt = 0; nt < 4; ++nt)
      bfr[nt] = *(const bf16x8*)&Bs[cur][(wn + nt * 16 + c16) * 32 + ((g ^ rsw) * 8)];
#pragma unroll
    for (int mt = 0; mt < 2; ++mt)
#pragma unroll
      for (int nt = 0; nt < 4; ++nt)
        acc[mt][nt] = mfma16(af[mt], bfr[nt], acc[mt][nt]);
    __syncthreads();  // drains vmcnt -> next buffer staged
    cur ^= 1;
  }
#undef STAGE_O

#pragma unroll
  for (int mt = 0; mt < 2; ++mt)
#pragma unroll
    for (int nt = 0; nt < 4; ++nt) {
      int n = n0 + wn + nt * 16 + c16;
      float bb = bo[n];
#pragma unroll
      for (int r = 0; r < 4; ++r) {
        int m = m0 + wm + mt * 16 + g * 4 + r;
        C[(size_t)m * 1024 + n] = acc[mt][nt][r] + bb;
      }
    }
}

// ---------------------------------------------------------------------------
extern "C" void kernel_launch(void* const* d_in, const int* in_sizes, int n_in,
                              void* d_out, int out_size, void* d_ws, size_t ws_size,
                              hipStream_t stream) {
  const float* query = (const float*)d_in[0];
  const float* key_  = (const float*)d_in[1];
  const float* value = (const float*)d_in[2];
  const float* Wq = (const float*)d_in[3];
  const float* bq = (const float*)d_in[4];
  const float* Wk = (const float*)d_in[5];
  const float* bk = (const float*)d_in[6];
  const float* Wv = (const float*)d_in[7];
  const float* bv = (const float*)d_in[8];
  const float* Wo = (const float*)d_in[9];
  const float* bo = (const float*)d_in[10];
  float* out = (float*)d_out;

  char* ws = (char*)d_ws;
  const size_t MB = 1024 * 1024;
  bf16* Wt  = (bf16*)(ws);              // 4 x [1024][1024] bf16 = 8 MB
  bf16* Qp  = (bf16*)(ws + 8 * MB);     // [4096][1024] bf16 (pre-scaled)
  bf16* Kp  = (bf16*)(ws + 16 * MB);    // [4096][1024]
  bf16* Vt  = (bf16*)(ws + 24 * MB);    // [32][64][2048]
  bf16* AO  = (bf16*)(ws + 32 * MB);    // attn out [4096][1024]

  dim3 blk(256);
  wt_kernel<<<dim3(256, 4), blk, 0, stream>>>(Wq, Wk, Wv, Wo, Wt);
  gemm_qkv<<<dim3(32, 8, 3), blk, 0, stream>>>(query, key_, value, Wt,
                                               bq, bk, bv, Qp, Kp, Vt);
  flash_kernel<<<dim3(512), blk, 0, stream>>>(Qp, Kp, Vt, AO);
  gemm_o<<<dim3(64, 8), blk, 0, stream>>>(AO, Wt + (size_t)3 * 1024 * 1024, bo, out);
}